// Round 1
// baseline (781.965 us; speedup 1.0000x reference)
//
#include <hip/hip_runtime.h>
#include <math.h>
#include <cstdint>
#include <cstddef>

// B=2, T=1024, C=4096, H=32, G=8, D=128, rep=4, M=B*T=2048
typedef __bf16 bf16_t;
typedef __bf16 bf16x8 __attribute__((ext_vector_type(8)));
typedef float f32x4 __attribute__((ext_vector_type(4)));

#define MFMA16(a, b, c) __builtin_amdgcn_mfma_f32_16x16x32_bf16(a, b, c, 0, 0, 0)

__device__ __forceinline__ void stage16(const void* g, void* l) {
  __builtin_amdgcn_global_load_lds(
      (const __attribute__((address_space(1))) unsigned int*)g,
      (__attribute__((address_space(3))) unsigned int*)l, 16, 0, 0);
}

// ---------------- convert fp32 -> bf16 ----------------
__global__ void k_convert(const float* __restrict__ in, bf16_t* __restrict__ out, int n) {
  int i = (blockIdx.x * blockDim.x + threadIdx.x) * 4;
  if (i >= n) return;
  float4 v = *(const float4*)(in + i);
  out[i + 0] = (bf16_t)v.x;
  out[i + 1] = (bf16_t)v.y;
  out[i + 2] = (bf16_t)v.z;
  out[i + 3] = (bf16_t)v.w;
}

// ---------------- transpose+convert: out[c][r] = in[r][c] ----------------
// block (32,8), grid (C/32, R/32)
__global__ void k_transpose(const float* __restrict__ in, bf16_t* __restrict__ out,
                            int R, int C) {
  __shared__ float t[32][33];
  int r0 = blockIdx.y * 32, c0 = blockIdx.x * 32;
  int tx = threadIdx.x, ty = threadIdx.y;
#pragma unroll
  for (int i = 0; i < 4; i++)
    t[ty + i * 8][tx] = in[(size_t)(r0 + ty + i * 8) * C + (c0 + tx)];
  __syncthreads();
#pragma unroll
  for (int i = 0; i < 4; i++)
    out[(size_t)(c0 + ty + i * 8) * R + (r0 + tx)] = (bf16_t)t[tx][ty + i * 8];
}

// ---------------- GEMM: C[M][N] = A[M][K]bf16 * BT[N][K]bf16 (+bias), fp32 out ----
// m97 structure: 128x128 tile, BK=32, 256 thr = 4 waves (each 64x64), global_load_lds
__global__ __launch_bounds__(256) void k_gemm_bt(
    const bf16_t* __restrict__ A, const bf16_t* __restrict__ BT,
    float* __restrict__ C, const float* __restrict__ bias,
    int M, int N, int K) {
  __shared__ __align__(16) bf16_t As[128 * 32];
  __shared__ __align__(16) bf16_t Bs[128 * 32];
  int tid = threadIdx.x;
  int w = tid >> 6, lane = tid & 63, quad = lane >> 4, l16 = lane & 15;
  int n0 = blockIdx.x * 128, m0 = blockIdx.y * 128;
  int wm = (w >> 1) * 64, wn = (w & 1) * 64;
  const char* Ab = (const char*)A + (size_t)m0 * K * 2;
  const char* Bb = (const char*)BT + (size_t)n0 * K * 2;
  size_t rb = (size_t)K * 2;
  f32x4 acc[4][4] = {};
  for (int k0 = 0; k0 < K; k0 += 32) {
    __syncthreads();
#pragma unroll
    for (int it = 0; it < 2; ++it) {
      int off = it * 4096 + tid * 16;   // byte offset in 8KB tile
      int row = off >> 6;               // 64 B per row (32 bf16)
      int colb = off & 63;
      stage16(Ab + (size_t)row * rb + (size_t)k0 * 2 + colb, (char*)As + off);
      stage16(Bb + (size_t)row * rb + (size_t)k0 * 2 + colb, (char*)Bs + off);
    }
    __syncthreads();
    bf16x8 af[4], bfr[4];
#pragma unroll
    for (int i = 0; i < 4; i++)
      af[i] = *(const bf16x8*)&As[(wm + i * 16 + l16) * 32 + quad * 8];
#pragma unroll
    for (int j = 0; j < 4; j++)
      bfr[j] = *(const bf16x8*)&Bs[(wn + j * 16 + l16) * 32 + quad * 8];
#pragma unroll
    for (int i = 0; i < 4; i++)
#pragma unroll
      for (int j = 0; j < 4; j++)
        acc[i][j] = MFMA16(af[i], bfr[j], acc[i][j]);
  }
#pragma unroll
  for (int i = 0; i < 4; i++) {
#pragma unroll
    for (int j = 0; j < 4; j++) {
      int col = n0 + wn + j * 16 + l16;
      float bv = bias ? bias[col] : 0.0f;
#pragma unroll
      for (int r = 0; r < 4; r++) {
        int row = m0 + wm + i * 16 + quad * 4 + r;
        C[(size_t)row * N + col] = acc[i][j][r] + bv;
      }
    }
  }
}

// ---------------- RoPE: in [B*T][NH*128] fp32 -> out [B][NH][T][128] bf16 -------
// block 256 (4 rows), lane handles pair (2*lane, 2*lane+1). T hardcoded 1024.
__global__ __launch_bounds__(256) void k_rope(const float* __restrict__ in,
                                              bf16_t* __restrict__ out,
                                              int NH, float scale) {
  int row = blockIdx.x * 4 + (threadIdx.x >> 6);
  int lane = threadIdx.x & 63;
  int h = row % NH;
  int bt = row / NH;
  int t = bt & 1023;
  int b = bt >> 10;
  const float* src = in + (size_t)bt * ((size_t)NH * 128) + h * 128 + lane * 2;
  float2 x = *(const float2*)src;
  float freq = powf(10000.0f, -(float)lane / 64.0f);
  float ang = (float)t * freq;
  float s, c;
  sincosf(ang, &s, &c);
  float orr = (x.x * c - x.y * s) * scale;
  float oi = (x.x * s + x.y * c) * scale;
  bf16_t* dst = out + ((size_t)(b * NH + h) * 1024 + t) * 128 + lane * 2;
  dst[0] = (bf16_t)orr;
  dst[1] = (bf16_t)oi;
}

// ---------------- V transpose: Vf[B*T][G*128] fp32 -> Vt[B][G][128][T] bf16 -----
// block (32,8), grid (T/32, G*4, B)
__global__ void k_transpose_v(const float* __restrict__ Vf, bf16_t* __restrict__ Vt) {
  __shared__ float t[32][33];
  int b = blockIdx.z;
  int g = blockIdx.y >> 2;
  int d0 = (blockIdx.y & 3) * 32;
  int t0 = blockIdx.x * 32;
  int tx = threadIdx.x, ty = threadIdx.y;
#pragma unroll
  for (int i = 0; i < 4; i++)
    t[ty + i * 8][tx] = Vf[(size_t)(b * 1024 + t0 + ty + i * 8) * 1024 + g * 128 + d0 + tx];
  __syncthreads();
#pragma unroll
  for (int i = 0; i < 4; i++)
    Vt[((size_t)(b * 8 + g) * 128 + d0 + ty + i * 8) * 1024 + t0 + tx] =
        (bf16_t)t[tx][ty + i * 8];
}

// ---------------- flash attention -----------------------------------------------
// Q [B][H][T][128] bf16 (pre-scaled by 1/sqrt(D)), K [B][G][T][128] bf16,
// V [B][G][128][T] bf16 (transposed), O [B*T][H*128] bf16.
// grid (T/64, H, B), 256 thr = 4 waves; wave w owns q-rows w*16..w*16+15 of tile.
__global__ __launch_bounds__(256) void k_attn(
    const bf16_t* __restrict__ Q, const bf16_t* __restrict__ K,
    const bf16_t* __restrict__ V, bf16_t* __restrict__ O) {
  __shared__ __align__(16) bf16_t Qs[64 * 128];   // [q][d]   16 KB
  __shared__ __align__(16) bf16_t Ks[64 * 128];   // [key][d] 16 KB
  __shared__ __align__(16) bf16_t Vs[128 * 64];   // [d][key] 16 KB
  __shared__ __align__(16) bf16_t Ps[4 * 16 * 64];// per-wave [16][64] 8 KB
  int tid = threadIdx.x;
  int w = tid >> 6, lane = tid & 63, quad = lane >> 4, l16 = lane & 15;
  int b = blockIdx.z, h = blockIdx.y;
  int g = h >> 2;  // rep = 4
  int q0 = blockIdx.x * 64;

  const char* Qg = (const char*)Q + ((size_t)(b * 32 + h) * 1024 + q0) * 256;
#pragma unroll
  for (int it = 0; it < 4; ++it) {
    int off = it * 4096 + tid * 16;
    stage16(Qg + off, (char*)Qs + off);
  }
  __syncthreads();

  bf16x8 qf[4];
#pragma unroll
  for (int kk = 0; kk < 4; ++kk)
    qf[kk] = *(const bf16x8*)&Qs[(w * 16 + l16) * 128 + kk * 32 + quad * 8];

  f32x4 Oacc[8] = {};
  float m_i[4], l_i[4];
#pragma unroll
  for (int r = 0; r < 4; r++) { m_i[r] = -INFINITY; l_i[r] = 0.0f; }

  const char* Kg = (const char*)K + ((size_t)(b * 8 + g) * 1024) * 256;
  const char* Vg = (const char*)V + ((size_t)(b * 8 + g) * 128) * 2048;
  int qrow = q0 + w * 16 + quad * 4;  // + r

  for (int kt = 0; kt <= (int)blockIdx.x; ++kt) {
    int k0 = kt * 64;
    __syncthreads();  // previous iter's LDS reads done
#pragma unroll
    for (int it = 0; it < 4; ++it) {
      int off = it * 4096 + tid * 16;
      stage16(Kg + (size_t)k0 * 256 + off, (char*)Ks + off);
    }
#pragma unroll
    for (int it = 0; it < 4; ++it) {
      int d = it * 32 + (tid >> 3);
      int cb = (tid & 7) * 16;
      stage16(Vg + (size_t)d * 2048 + (size_t)k0 * 2 + cb, (char*)Vs + it * 4096 + tid * 16);
    }
    __syncthreads();

    // S = Q K^T : wave's 16 rows x 64 keys (4 n-tiles, K=128 -> 4 mfma each)
    f32x4 S[4];
#pragma unroll
    for (int nt = 0; nt < 4; ++nt) {
      f32x4 s = {0.f, 0.f, 0.f, 0.f};
#pragma unroll
      for (int kk = 0; kk < 4; ++kk) {
        bf16x8 kf = *(const bf16x8*)&Ks[(nt * 16 + l16) * 128 + kk * 32 + quad * 8];
        s = MFMA16(qf[kk], kf, s);
      }
      S[nt] = s;
    }

    // online softmax over the wave's full 64-key slice (intra-quad shuffles)
    float alpha[4];
#pragma unroll
    for (int r = 0; r < 4; r++) {
      int rowg = qrow + r;
      float sv[4];
      float mx = -INFINITY;
#pragma unroll
      for (int nt = 0; nt < 4; ++nt) {
        float v = S[nt][r];
        int col = k0 + nt * 16 + l16;
        v = (col <= rowg) ? v : -INFINITY;
        sv[nt] = v;
        mx = fmaxf(mx, v);
      }
      mx = fmaxf(mx, __shfl_xor(mx, 1));
      mx = fmaxf(mx, __shfl_xor(mx, 2));
      mx = fmaxf(mx, __shfl_xor(mx, 4));
      mx = fmaxf(mx, __shfl_xor(mx, 8));
      float mn = fmaxf(m_i[r], mx);
      float al = __expf(m_i[r] - mn);  // exp(-inf)=0, mn always finite
      float sum = 0.f;
#pragma unroll
      for (int nt = 0; nt < 4; ++nt) {
        float p = __expf(sv[nt] - mn);
        sv[nt] = p;
        sum += p;
      }
      sum += __shfl_xor(sum, 1);
      sum += __shfl_xor(sum, 2);
      sum += __shfl_xor(sum, 4);
      sum += __shfl_xor(sum, 8);
      m_i[r] = mn;
      l_i[r] = l_i[r] * al + sum;
      alpha[r] = al;
#pragma unroll
      for (int nt = 0; nt < 4; ++nt)
        Ps[w * 1024 + (quad * 4 + r) * 64 + nt * 16 + l16] = (bf16_t)sv[nt];
    }
    __syncthreads();  // P visible (C-layout -> A-layout via LDS)

    // O = diag(alpha) O + P V   (8 d-tiles, K=64 keys -> 2 mfma each)
    bf16x8 pf[2];
#pragma unroll
    for (int kk = 0; kk < 2; ++kk)
      pf[kk] = *(const bf16x8*)&Ps[w * 1024 + l16 * 64 + kk * 32 + quad * 8];
#pragma unroll
    for (int nt = 0; nt < 8; ++nt) {
      f32x4 o = Oacc[nt];
#pragma unroll
      for (int r = 0; r < 4; r++) o[r] *= alpha[r];
#pragma unroll
      for (int kk = 0; kk < 2; ++kk) {
        bf16x8 vf = *(const bf16x8*)&Vs[(nt * 16 + l16) * 64 + kk * 32 + quad * 8];
        o = MFMA16(pf[kk], vf, o);
      }
      Oacc[nt] = o;
    }
  }

  // epilogue: normalize by l, write O[b*T+t][h*128+d] bf16
#pragma unroll
  for (int nt = 0; nt < 8; ++nt) {
#pragma unroll
    for (int r = 0; r < 4; r++) {
      int t = qrow + r;
      float val = Oacc[nt][r] / l_i[r];
      O[((size_t)(b * 1024 + t)) * 4096 + h * 128 + nt * 16 + l16] = (bf16_t)val;
    }
  }
}

extern "C" void kernel_launch(void* const* d_in, const int* in_sizes, int n_in,
                              void* d_out, int out_size, void* d_ws, size_t ws_size,
                              hipStream_t stream) {
  const float* x  = (const float*)d_in[0];   // [2,1024,4096]
  const float* Wq = (const float*)d_in[1];   // [4096,4096]
  const float* Wk = (const float*)d_in[2];   // [4096,1024]
  const float* Wv = (const float*)d_in[3];   // [4096,1024]
  const float* Wo = (const float*)d_in[4];   // [4096,4096]
  const float* bo = (const float*)d_in[5];   // [4096]
  float* out = (float*)d_out;                // [2,1024,4096]

  char* p = (char*)d_ws;
  bf16_t* Xb  = (bf16_t*)p; p += (size_t)2048 * 4096 * 2;  // 16 MB
  bf16_t* WqT = (bf16_t*)p; p += (size_t)4096 * 4096 * 2;  // 32 MB
  bf16_t* WkT = (bf16_t*)p; p += (size_t)1024 * 4096 * 2;  //  8 MB
  bf16_t* WvT = (bf16_t*)p; p += (size_t)1024 * 4096 * 2;  //  8 MB
  bf16_t* WoT = (bf16_t*)p; p += (size_t)4096 * 4096 * 2;  // 32 MB
  float*  Qf  = (float*)p;                                  // 32 MB (dead after rope)
  bf16_t* Ob  = (bf16_t*)p; p += (size_t)2048 * 4096 * 4;  // Ob aliases Qf region
  float*  Kf  = (float*)p; p += (size_t)2048 * 1024 * 4;   //  8 MB
  float*  Vf  = (float*)p; p += (size_t)2048 * 1024 * 4;   //  8 MB
  bf16_t* Qb  = (bf16_t*)p; p += (size_t)2048 * 4096 * 2;  // 16 MB
  bf16_t* Kb  = (bf16_t*)p; p += (size_t)2048 * 1024 * 2;  //  4 MB
  bf16_t* Vt  = (bf16_t*)p; p += (size_t)2048 * 1024 * 2;  //  4 MB

  dim3 tb(32, 8);
  // 1. convert x to bf16
  k_convert<<<8192, 256, 0, stream>>>(x, Xb, 2048 * 4096);
  // 2. transpose weights to [N][K] bf16
  k_transpose<<<dim3(128, 128), tb, 0, stream>>>(Wq, WqT, 4096, 4096);
  k_transpose<<<dim3(32, 128),  tb, 0, stream>>>(Wk, WkT, 4096, 1024);
  k_transpose<<<dim3(32, 128),  tb, 0, stream>>>(Wv, WvT, 4096, 1024);
  k_transpose<<<dim3(128, 128), tb, 0, stream>>>(Wo, WoT, 4096, 4096);
  // 3. QKV projections (fp32 out)
  k_gemm_bt<<<dim3(32, 16), 256, 0, stream>>>(Xb, WqT, Qf, nullptr, 2048, 4096, 4096);
  k_gemm_bt<<<dim3(8, 16),  256, 0, stream>>>(Xb, WkT, Kf, nullptr, 2048, 1024, 4096);
  k_gemm_bt<<<dim3(8, 16),  256, 0, stream>>>(Xb, WvT, Vf, nullptr, 2048, 1024, 4096);
  // 4. RoPE (Q pre-scaled by 1/sqrt(128)) + V transpose
  k_rope<<<16384, 256, 0, stream>>>(Qf, Qb, 32, 0.08838834764831845f);
  k_rope<<<4096, 256, 0, stream>>>(Kf, Kb, 8, 1.0f);
  k_transpose_v<<<dim3(32, 32, 2), tb, 0, stream>>>(Vf, Vt);
  // 5. flash attention
  k_attn<<<dim3(16, 32, 2), 256, 0, stream>>>(Qb, Kb, Vt, Ob);
  // 6. output projection + bias -> fp32 out
  k_gemm_bt<<<dim3(32, 16), 256, 0, stream>>>(Ob, WoT, out, bo, 2048, 4096, 4096);
}